// Round 6
// baseline (13722.411 us; speedup 1.0000x reference)
//
#include <hip/hip_runtime.h>
#include <cstdint>
#include <cstddef>

// Problem constants
#define T_ 256
#define B_ 64
#define E_ 256
#define H_ 512
#define NTAG 32
#define CHK 32            // layer-0 time-chunk length
#define CHK1 16           // layer-1 time-chunk length (halved so xp double-buffers fit in place)
#define HSLOT 33          // rolling h-history slots (no address reuse within a launch)
#define SPIN_MAX (1<<20)  // failsafe: terminates cleanly, >>1000x normal wait

// ---------------- workspace layout (float offsets), total ~226.1 MB ----------------
// x1: [T][256][B][4]  layer-0 output
static constexpr size_t OX1  = 0;
static constexpr size_t SX1  = (size_t)T_*256*B_*4;           // 16,777,216
// x2: [T][256][B][4]  layer-1 output; x0 (embeddings) ALIASES its head
static constexpr size_t OX2  = OX1 + SX1;
static constexpr size_t SX2  = SX1;
static constexpr size_t OX0  = OX2;                           // [T][64][B][4] = 4,194,304 floats
static constexpr size_t SX0  = (size_t)T_*64*B_*4;
// xp region: 8,388,608 floats.
//   layer 0: buffer A = OXP (dir-stride SXPC0); buffer B = OX2+SX0 (dead x2 tail)
//   layer 1: buffer A = OXP, buffer B = OXP + 2*SXPC1 (both dir-stride SXPC1)
static constexpr size_t OXP  = OX2 + SX2;
static constexpr size_t SXPC0 = (size_t)CHK*2048*B_;          // 4,194,304 per dir (CHK=32)
static constexpr size_t SXPC1 = (size_t)CHK1*2048*B_;         // 2,097,152 per dir (CHK=16)
static constexpr size_t SXP  = 2*SXPC0;
static constexpr size_t OXPB0 = OX2 + SX0;                    // layer-0 buffer B (8.4M <= 12.6M free)
// whh packs: per layer: [2 dir][512 u][512 k][4 gate]
static constexpr size_t OWHH0 = OXP + SXP;
static constexpr size_t SWHH  = (size_t)2*512*512*4;          // 2,097,152
static constexpr size_t OWHH1 = OWHH0 + SWHH;
// wih packs: [2 dir][128 g][K][16 jj]
static constexpr size_t OWIH0 = OWHH1 + SWHH;
static constexpr size_t SWIH0 = (size_t)2*2048*256;
static constexpr size_t OWIH1 = OWIH0 + SWIH0;
static constexpr size_t SWIH1 = (size_t)2*2048*1024;
// wout pack: [1024 k][32]
static constexpr size_t OWOUT = OWIH1 + SWIH1;
static constexpr size_t SWOUT = (size_t)1024*32;
// h history: [2 layer][2 dir][HSLOT][128 k4][64 b][4]
static constexpr size_t OHH   = OWOUT + SWOUT;
static constexpr size_t SHHL  = (size_t)2*HSLOT*32768;        // per layer (2 dir)
static constexpr size_t SHH   = 2*SHHL;
// cbuf: [2 layer][2 dir][512 u][64 b]
static constexpr size_t OCB   = OHH + SHH;
static constexpr size_t SCB   = (size_t)2*2*512*64;
// barrier flags: [2 layer][2 dir][128 blocks x 16 ints]
static constexpr size_t OBAR  = OCB + SCB;
static constexpr size_t SBAR  = (size_t)2*2*128*16;           // 8192 ints
// feats: [T][B][32]
static constexpr size_t OFE   = OBAR + SBAR;
static constexpr size_t SFE   = (size_t)T_*B_*NTAG;
// backpointers (bytes): [255][B][32]
static constexpr size_t OBP   = OFE + SFE;
static constexpr size_t SBP   = (size_t)T_*B_*NTAG/4;
static constexpr size_t WS_FLOATS = OBP + SBP;                // ~226.1 MB (unchanged)

__device__ __forceinline__ float sigf(float x){ return 1.0f/(1.0f + expf(-x)); }

// ---------------- weight packing ----------------
// whh pack (per dir matrix): out[(u*512 + k)*4 + gate] = w[(gate*512 + u)*512 + k]
__global__ void pack_whh(const float* __restrict__ w, float* __restrict__ out){
  int id = blockIdx.x*256 + threadIdx.x;            // grid 4096
  int gate = id & 3, k = (id>>2) & 511, u = id >> 11;
  out[id] = w[((size_t)gate*512 + u)*512 + k];
}
// wih pack: out[g][k][jj] jj in [0,16), row = g*16+jj
__global__ void pack_wih(const float* __restrict__ w, float* __restrict__ out, int K, int kshift){
  int id = blockIdx.x*256 + threadIdx.x;            // 2048*K threads
  int k = id & (K-1); int jj = (id>>kshift)&15; int g = id>>(kshift+4);
  out[((size_t)g*K + k)*16 + jj] = w[(size_t)(g*16+jj)*K + k];
}
// wout pack: out[k][32]
__global__ void pack_wout(const float* __restrict__ w, float* __restrict__ out){
  int id = blockIdx.x*256 + threadIdx.x;            // 32*1024
  int k = id & 1023, jj = id>>10;
  out[k*32 + jj] = w[id];
}

// ---------------- embedding gather (to [t][e4][b][4]) ----------------
__global__ void gather_emb(const int* __restrict__ sent, const float* __restrict__ emb,
                           float* __restrict__ x0){
  int t = blockIdx.x; int lane = threadIdx.x & 63; int w = threadIdx.x >> 6;
  int s = sent[t*B_ + lane];
  const float4* er = (const float4*)emb + (size_t)s*(E_/4);
  float4* xo = (float4*)x0 + (size_t)t*64*64;
  #pragma unroll
  for (int q=0; q<16; ++q){
    int e4 = w*16 + q;
    xo[e4*64 + lane] = er[e4];
  }
}

// ---------------- standalone input projection GEMM (chunk 0 of each layer) ----------------
__global__ __launch_bounds__(256) void proj_kernel(
    const float* __restrict__ xin, const float* __restrict__ wpack,
    const float* __restrict__ bihf, const float* __restrict__ bhhf,
    const float* __restrict__ bihr, const float* __restrict__ bhhr,
    float* __restrict__ xp, size_t xp_ds, int K, int t0){
  int jg = blockIdx.x, i = blockIdx.y, dir = blockIdx.z;
  int t = dir ? (T_-1 - (t0 + i)) : (t0 + i);
  int lane = threadIdx.x & 63;
  int w = __builtin_amdgcn_readfirstlane((int)threadIdx.x) >> 6;
  int kq = K >> 2;                 // k per wave
  int n4 = kq >> 2;                // float4 iters
  int k40 = (w*kq) >> 2;
  const float4* xi = (const float4*)xin + (size_t)t*(K>>2)*64;
  size_t pstride = (size_t)K*16;
  const float* wp = wpack + (size_t)dir*2048*K + (size_t)(jg*2)*pstride + (size_t)w*kq*16;
  float acc[2][16];
  #pragma unroll
  for (int p=0;p<2;p++)
    #pragma unroll
    for (int jj=0;jj<16;jj++) acc[p][jj] = 0.f;
  for (int k4=0; k4<n4; ++k4){
    float4 h = xi[(k40+k4)*64 + lane];
    float hv[4] = {h.x, h.y, h.z, h.w};
    #pragma unroll
    for (int p=0;p<2;p++){
      const float* wv = wp + p*pstride + k4*64;
      #pragma unroll
      for (int ii=0;ii<4;ii++)
        #pragma unroll
        for (int jj=0;jj<16;jj++)
          acc[p][jj] = fmaf(wv[ii*16+jj], hv[ii], acc[p][jj]);
    }
  }
  __shared__ float red[4][32][64];
  #pragma unroll
  for (int p=0;p<2;p++)
    #pragma unroll
    for (int jj=0;jj<16;jj++) red[w][p*16+jj][lane] = acc[p][jj];
  __syncthreads();
  const float* b1 = dir ? bihr : bihf;
  const float* b2 = dir ? bhhr : bhhf;
  float* xpd = xp + (size_t)dir*xp_ds + (size_t)i*2048*64;
  #pragma unroll
  for (int q=0;q<8;q++){
    int rr = w*8 + q;
    float v = red[0][rr][lane] + red[1][rr][lane] + red[2][rr][lane] + red[3][rr][lane];
    int row = jg*32 + rr;
    v += b1[row] + b2[row];
    xpd[(size_t)row*64 + lane] = v;
  }
}

// ---------------- fused persistent LSTM chunk + next-chunk projection ----------------
// Grid 512 x 256 thr, __launch_bounds__(256,2) => 2 blocks/CU capacity guaranteed
// (LDS 49KB, VGPR<=256) => ALL 512 blocks resident => rec spin protocol safe.
//   blocks 0..255:  rec for chunk [step0, step0+nsteps) -- byte-identical to the
//     R0 386us kernel (direct 128-flag poll, relaxed agent atomics + vmcnt(0)
//     drain, rolling 33-slot h history), xp dir-stride parameterized, with
//     s_setprio(1) so co-running proj waves don't displace the critical path.
//   blocks 256..511: persistent proj workers computing chunk c+1's xp into the
//     OTHER xp buffer (projK==0 -> none). Proj reads only the layer INPUT
//     (x0 / x1, fully materialized) => zero dependency on concurrent rec.
//     Mapping: jg = p&63 (keeps jg%8==p%8 XCD pinning), r = p>>6 in [0,4);
//     each block does projCHK/2 (i,dir) tiles for its jg.
__global__ __launch_bounds__(256,2) void fused_kernel(
    const float* __restrict__ xpA, const float* __restrict__ whh,
    float* __restrict__ xout, float* __restrict__ hh, float* __restrict__ cb0,
    int* __restrict__ flags, int step0, int nsteps, size_t xpA_ds,
    const float* __restrict__ xin, const float* __restrict__ wih,
    const float* __restrict__ bihf, const float* __restrict__ bhhf,
    const float* __restrict__ bihr, const float* __restrict__ bhhr,
    float* __restrict__ xpB, size_t xpB_ds, int projK, int projT0, int projCHK){
  __shared__ float red[4][16][64];              // rec: [wave][u*4+gate][lane]
  __shared__ float hlds[256];                   // rec: [64 b][4 u]
  __shared__ float redp[4][32][64];             // proj reduction
  int bid = blockIdx.x;
  int lane = threadIdx.x & 63;
  int w = __builtin_amdgcn_readfirstlane((int)threadIdx.x >> 6);

  if (bid >= 256){
    // ---------------- proj worker ----------------
    if (projK == 0) return;
    int p = bid - 256;
    int jg = p & 63, r = p >> 6;                // r in [0,4)
    int tpb = projCHK >> 1;                     // tiles per block
    int kq = projK >> 2;
    int n4 = kq >> 2;
    int k40 = (w*kq) >> 2;
    size_t pstride = (size_t)projK*16;
    for (int q=0; q<tpb; ++q){
      int idx = r*tpb + q;                      // [0, 2*projCHK)
      int dirp = (idx >= projCHK) ? 1 : 0;
      int i = idx - dirp*projCHK;
      int t = dirp ? (T_-1 - (projT0 + i)) : (projT0 + i);
      const float4* xi = (const float4*)xin + (size_t)t*(projK>>2)*64;
      const float* wp = wih + (size_t)dirp*2048*projK + (size_t)(jg*2)*pstride + (size_t)w*kq*16;
      float acc[2][16];
      #pragma unroll
      for (int pp=0;pp<2;pp++)
        #pragma unroll
        for (int jj=0;jj<16;jj++) acc[pp][jj] = 0.f;
      for (int k4=0; k4<n4; ++k4){
        float4 h = xi[(k40+k4)*64 + lane];
        float hv[4] = {h.x, h.y, h.z, h.w};
        #pragma unroll
        for (int pp=0;pp<2;pp++){
          const float* wv = wp + pp*pstride + k4*64;
          #pragma unroll
          for (int ii=0;ii<4;ii++)
            #pragma unroll
            for (int jj=0;jj<16;jj++)
              acc[pp][jj] = fmaf(wv[ii*16+jj], hv[ii], acc[pp][jj]);
        }
      }
      #pragma unroll
      for (int pp=0;pp<2;pp++)
        #pragma unroll
        for (int jj=0;jj<16;jj++) redp[w][pp*16+jj][lane] = acc[pp][jj];
      __syncthreads();
      const float* b1 = dirp ? bihr : bihf;
      const float* b2 = dirp ? bhhr : bhhf;
      float* xpd = xpB + (size_t)dirp*xpB_ds + (size_t)i*2048*64;
      #pragma unroll
      for (int q2=0;q2<8;q2++){
        int rr = w*8 + q2;
        float v = redp[0][rr][lane] + redp[1][rr][lane] + redp[2][rr][lane] + redp[3][rr][lane];
        int row = jg*32 + rr;
        v += b1[row] + b2[row];
        xpd[(size_t)row*64 + lane] = v;
      }
      __syncthreads();                          // redp reused next tile
    }
    return;
  }

  // ---------------- rec block (R0 protocol, verbatim) ----------------
  __builtin_amdgcn_s_setprio(1);                // favor rec over proj co-runners
  int dir = bid & 1, g = bid >> 1;
  const float* xpd = xpA + (size_t)dir*xpA_ds;
  const float* wbase = whh + (size_t)dir*1048576 + (size_t)g*4*2048;  // [u][k][gate]
  float* hhd = hh + (size_t)dir*((size_t)HSLOT*32768);
  float* cb = cb0 + dir*32768;
  int* fl = flags + dir*(128*16);
  int uo = g*4 + w;                             // unit finalized by this wave
  float c = cb[uo*64 + lane];
  size_t xb = ((size_t)uo)*64 + lane;
  float x0v = xpd[xb], x1v = xpd[xb+32768], x2v = xpd[xb+65536], x3v = xpd[xb+98304];
  for (int s=0; s<nsteps; ++s){
    int gstep = step0 + s;
    int t = dir ? (T_-1-gstep) : gstep;
    const float4* hp = (const float4*)(hhd + (size_t)(gstep % HSLOT)*32768);
    // stage this wave's k-quarter into registers: 32 independent loads in flight
    float4 hreg[32];
    #pragma unroll
    for (int i=0;i<32;i++) hreg[i] = hp[(w*32+i)*64 + lane];
    float acc[4][4];
    #pragma unroll
    for (int cu=0;cu<4;cu++)
      #pragma unroll
      for (int gt=0;gt<4;gt++) acc[cu][gt]=0.f;
    #pragma unroll
    for (int i=0;i<32;i++){
      float hv[4] = {hreg[i].x, hreg[i].y, hreg[i].z, hreg[i].w};
      #pragma unroll
      for (int cu=0; cu<4; cu++){
        const float4* wr = (const float4*)(wbase + (size_t)cu*2048 + (size_t)(w*128 + i*4)*4);
        #pragma unroll
        for (int kk=0;kk<4;kk++){
          float4 w4 = wr[kk];
          acc[cu][0] = fmaf(w4.x, hv[kk], acc[cu][0]);
          acc[cu][1] = fmaf(w4.y, hv[kk], acc[cu][1]);
          acc[cu][2] = fmaf(w4.z, hv[kk], acc[cu][2]);
          acc[cu][3] = fmaf(w4.w, hv[kk], acc[cu][3]);
        }
      }
    }
    #pragma unroll
    for (int cu=0;cu<4;cu++)
      #pragma unroll
      for (int gt=0;gt<4;gt++) red[w][cu*4+gt][lane] = acc[cu][gt];
    __syncthreads();
    float gv[4];
    #pragma unroll
    for (int gt=0;gt<4;gt++)
      gv[gt] = red[0][w*4+gt][lane] + red[1][w*4+gt][lane]
             + red[2][w*4+gt][lane] + red[3][w*4+gt][lane];
    gv[0] += x0v; gv[1] += x1v; gv[2] += x2v; gv[3] += x3v;
    float iv = sigf(gv[0]), fv = sigf(gv[1]);
    float gg = tanhf(gv[2]), ov = sigf(gv[3]);
    c = fv*c + iv*gg;
    float h = ov*tanhf(c);
    hlds[lane*4 + w] = h;
    __syncthreads();
    if (w == 0){
      // publish h quad: write-through coherent stores (2x u64 per lane = 1 KB)
      float4 hv4 = ((const float4*)hlds)[lane];
      union { float4 f; unsigned long long qq[2]; } uu; uu.f = hv4;
      unsigned long long* dst = (unsigned long long*)
          (hhd + (size_t)((gstep+1) % HSLOT)*32768 + (size_t)g*256 + (size_t)lane*4);
      __hip_atomic_store(dst+0, uu.qq[0], __ATOMIC_RELAXED, __HIP_MEMORY_SCOPE_AGENT);
      __hip_atomic_store(dst+1, uu.qq[1], __ATOMIC_RELAXED, __HIP_MEMORY_SCOPE_AGENT);
    } else if (w == 1){
      float4 hv4 = ((const float4*)hlds)[lane];
      float4* xo = (float4*)(xout + (size_t)t*65536 + (size_t)(dir*128 + g)*256);
      xo[lane] = hv4;
    }
    if (s < nsteps-1){
      if (w == 0){
        asm volatile("s_waitcnt vmcnt(0)" ::: "memory");   // h stores at coherence point
      }
      __syncthreads();
      if (threadIdx.x == 0)
        __hip_atomic_store(&fl[g*16], gstep+1, __ATOMIC_RELAXED, __HIP_MEMORY_SCOPE_AGENT);
      // prefetch next step's xp gates (overlaps poll latency)
      size_t xb2 = ((size_t)(s+1)*2048 + uo)*64 + lane;
      x0v = xpd[xb2]; x1v = xpd[xb2+32768]; x2v = xpd[xb2+65536]; x3v = xpd[xb2+98304];
      int tid = threadIdx.x;
      if (tid < 128){
        int target = gstep+1;
        int spins = 0;
        while (__hip_atomic_load(&fl[tid*16], __ATOMIC_RELAXED, __HIP_MEMORY_SCOPE_AGENT) < target){
          __builtin_amdgcn_s_sleep(1);
          if (++spins > SPIN_MAX) break;   // failsafe
        }
      }
      __syncthreads();
      asm volatile("" ::: "memory");      // keep h loads after the poll
    }
  }
  cb[uo*64 + lane] = c;   // persist cell state for the next chunk launch
}

// ---------------- output projection (feats) ----------------
__global__ __launch_bounds__(256) void feats_kernel(
    const float* __restrict__ x2, const float* __restrict__ wout,
    const float* __restrict__ bout, float* __restrict__ feats){
  int t = blockIdx.x; int lane = threadIdx.x & 63;
  int w = __builtin_amdgcn_readfirstlane((int)threadIdx.x) >> 6;
  const float4* xi = (const float4*)x2 + (size_t)t*16384;
  const float* wp = wout + (size_t)w*256*32;
  float acc[32];
  #pragma unroll
  for (int j=0;j<32;j++) acc[j] = 0.f;
  for (int k4=0;k4<64;k4++){
    float4 h = xi[(w*64 + k4)*64 + lane];
    float hv[4] = {h.x, h.y, h.z, h.w};
    const float* wv = wp + k4*128;
    #pragma unroll
    for (int ii=0;ii<4;ii++)
      #pragma unroll
      for (int j=0;j<32;j++)
        acc[j] = fmaf(wv[ii*32+j], hv[ii], acc[j]);
  }
  __shared__ float red[4][32][64];
  #pragma unroll
  for (int j=0;j<32;j++) red[w][j][lane] = acc[j];
  __syncthreads();
  __shared__ float tr[64*33];
  #pragma unroll
  for (int q=0;q<8;q++){
    int j = w*8 + q;
    float v = red[0][j][lane]+red[1][j][lane]+red[2][j][lane]+red[3][j][lane] + bout[j];
    tr[lane*33 + j] = v;
  }
  __syncthreads();
  float* fo = feats + (size_t)t*2048;
  int tid = threadIdx.x;
  #pragma unroll
  for (int q=0;q<8;q++){
    int idx = tid*8 + q;                 // = b*32 + j
    fo[idx] = tr[(idx>>5)*33 + (idx&31)];
  }
}

// ---------------- Viterbi decode ----------------
__global__ __launch_bounds__(64) void viterbi_kernel(
    const float* __restrict__ feats, const float* __restrict__ trans,
    const float* __restrict__ start, const float* __restrict__ stop,
    unsigned char* __restrict__ bp, float* __restrict__ out){
  int lane = threadIdx.x & 63;
  int b = blockIdx.x*2 + (lane>>5);
  int j = lane & 31;
  int base = lane & 32;
  float tr[32];
  #pragma unroll
  for (int k=0;k<32;k++) tr[k] = trans[j*32+k];
  float dp = start[j] + feats[b*32 + j];
  for (int t=1;t<T_;t++){
    float best = __shfl(dp, base, 64) + tr[0];
    int arg = 0;
    #pragma unroll
    for (int k=1;k<32;k++){
      float v = __shfl(dp, base + k, 64) + tr[k];
      if (v > best){ best = v; arg = k; }
    }
    dp = best + feats[((size_t)t*64 + b)*32 + j];
    bp[(size_t)(t-1)*2048 + b*32 + j] = (unsigned char)arg;
  }
  dp += stop[j];
  float bv = dp; int bi = j;
  #pragma unroll
  for (int off=1; off<32; off<<=1){
    float ov = __shfl_xor(bv, off, 64);
    int oi   = __shfl_xor(bi, off, 64);
    if (ov > bv || (ov == bv && oi < bi)){ bv = ov; bi = oi; }
  }
  if (j == 0){
    out[b] = bv;
    int cur = bi;
    out[64 + 255*64 + b] = (float)cur;
    for (int t=254;t>=0;t--){
      cur = bp[(size_t)t*2048 + b*32 + cur];
      out[64 + t*64 + b] = (float)cur;
    }
  }
}

// ---------------- launcher ----------------
extern "C" void kernel_launch(void* const* d_in, const int* in_sizes, int n_in,
                              void* d_out, int out_size, void* d_ws, size_t ws_size,
                              hipStream_t stream){
  const int*   sent      = (const int*)  d_in[0];
  const float* emb       = (const float*)d_in[1];
  const float* w_ih_l0f  = (const float*)d_in[2];
  const float* w_hh_l0f  = (const float*)d_in[3];
  const float* b_ih_l0f  = (const float*)d_in[4];
  const float* b_hh_l0f  = (const float*)d_in[5];
  const float* w_ih_l0r  = (const float*)d_in[6];
  const float* w_hh_l0r  = (const float*)d_in[7];
  const float* b_ih_l0r  = (const float*)d_in[8];
  const float* b_hh_l0r  = (const float*)d_in[9];
  const float* w_ih_l1f  = (const float*)d_in[10];
  const float* w_hh_l1f  = (const float*)d_in[11];
  const float* b_ih_l1f  = (const float*)d_in[12];
  const float* b_hh_l1f  = (const float*)d_in[13];
  const float* w_ih_l1r  = (const float*)d_in[14];
  const float* w_hh_l1r  = (const float*)d_in[15];
  const float* b_ih_l1r  = (const float*)d_in[16];
  const float* b_hh_l1r  = (const float*)d_in[17];
  const float* W_out     = (const float*)d_in[18];
  const float* b_out     = (const float*)d_in[19];
  const float* trans     = (const float*)d_in[20];
  const float* start_t   = (const float*)d_in[21];
  const float* stop_t    = (const float*)d_in[22];
  float* ws  = (float*)d_ws;
  float* out = (float*)d_out;

  // Guard: if scratch is too small, bail out cleanly (absmax fail, not a GPU fault).
  if (ws_size < WS_FLOATS * sizeof(float)) return;

  // zero h-history/c/flag state (ws is re-poisoned to 0xAA before every timed launch)
  hipMemsetAsync(ws + OHH, 0, (SHH + SCB + SBAR)*sizeof(float), stream);

  // weight packing (idempotent, runs every call)
  pack_whh<<<4096,256,0,stream>>>(w_hh_l0f, ws + OWHH0);
  pack_whh<<<4096,256,0,stream>>>(w_hh_l0r, ws + OWHH0 + 1048576);
  pack_whh<<<4096,256,0,stream>>>(w_hh_l1f, ws + OWHH1);
  pack_whh<<<4096,256,0,stream>>>(w_hh_l1r, ws + OWHH1 + 1048576);
  pack_wih<<<2048,256,0,stream>>>(w_ih_l0f, ws + OWIH0,           256, 8);
  pack_wih<<<2048,256,0,stream>>>(w_ih_l0r, ws + OWIH0 + 524288,  256, 8);
  pack_wih<<<8192,256,0,stream>>>(w_ih_l1f, ws + OWIH1,           1024, 10);
  pack_wih<<<8192,256,0,stream>>>(w_ih_l1r, ws + OWIH1 + 2097152, 1024, 10);
  pack_wout<<<128,256,0,stream>>>(W_out, ws + OWOUT);

  gather_emb<<<256,256,0,stream>>>(sent, emb, ws + OX0);

  int* bar = (int*)(ws + OBAR);

  // ---- layer 0: CHK=32, 8 fused launches; xp buffers OXP <-> OXPB0 ----
  {
    float* bufA = ws + OXP;
    float* bufB = ws + OXPB0;
    dim3 gp(64, CHK, 2);
    proj_kernel<<<gp,256,0,stream>>>(ws+OX0, ws+OWIH0,
                                     b_ih_l0f,b_hh_l0f,b_ih_l0r,b_hh_l0r,
                                     bufA, SXPC0, 256, 0);
    const int NCH = T_ / CHK;    // 8
    for (int c = 0; c < NCH; ++c){
      int projK = (c < NCH-1) ? 256 : 0;
      fused_kernel<<<512,256,0,stream>>>(
          bufA, ws+OWHH0, ws+OX1, ws+OHH, ws+OCB, bar, c*CHK, CHK, SXPC0,
          ws+OX0, ws+OWIH0, b_ih_l0f,b_hh_l0f,b_ih_l0r,b_hh_l0r,
          bufB, SXPC0, projK, (c+1)*CHK, CHK);
      float* tmp = bufA; bufA = bufB; bufB = tmp;
    }
  }
  // ---- layer 1: CHK=16, 16 fused launches; xp buffers OXP <-> OXP+2*SXPC1 ----
  {
    float* bufA = ws + OXP;
    float* bufB = ws + OXP + 2*SXPC1;
    dim3 gp(64, CHK1, 2);
    proj_kernel<<<gp,256,0,stream>>>(ws+OX1, ws+OWIH1,
                                     b_ih_l1f,b_hh_l1f,b_ih_l1r,b_hh_l1r,
                                     bufA, SXPC1, 1024, 0);
    const int NCH = T_ / CHK1;   // 16
    for (int c = 0; c < NCH; ++c){
      int projK = (c < NCH-1) ? 1024 : 0;
      fused_kernel<<<512,256,0,stream>>>(
          bufA, ws+OWHH1, ws+OX2, ws+OHH+SHHL, ws+OCB+65536, bar+4096,
          c*CHK1, CHK1, SXPC1,
          ws+OX1, ws+OWIH1, b_ih_l1f,b_hh_l1f,b_ih_l1r,b_hh_l1r,
          bufB, SXPC1, projK, (c+1)*CHK1, CHK1);
      float* tmp = bufA; bufA = bufB; bufB = tmp;
    }
  }
  // emission scores + decode
  feats_kernel<<<256,256,0,stream>>>(ws+OX2, ws+OWOUT, b_out, ws+OFE);
  viterbi_kernel<<<32,64,0,stream>>>(ws+OFE, trans, start_t, stop_t,
                                     (unsigned char*)(ws+OBP), out);
}

// Round 7
// 8947.597 us; speedup vs baseline: 1.5336x; 1.5336x over previous
//
#include <hip/hip_runtime.h>
#include <cstdint>
#include <cstddef>

// Problem constants
#define T_ 256
#define B_ 64
#define E_ 256
#define H_ 512
#define NTAG 32
#define CHK 32            // time-chunk length (T_/CHK rec launches per layer)
#define HSLOT 33          // rolling h-history slots (CHK+1; no address reuse within a launch)

// ---------------- workspace layout (float offsets), total ~226.1 MB ----------------
// x1: [T][256][B][4]  layer-0 output
static constexpr size_t OX1  = 0;
static constexpr size_t SX1  = (size_t)T_*256*B_*4;           // 16,777,216
// x2: [T][256][B][4]  layer-1 output; x0 (embeddings) ALIASES its head
static constexpr size_t OX2  = OX1 + SX1;
static constexpr size_t SX2  = SX1;
static constexpr size_t OX0  = OX2;                           // [T][64][B][4]
// xp: [2 dir][CHK][2048][B]
static constexpr size_t OXP  = OX2 + SX2;
static constexpr size_t SXPC = (size_t)CHK*2048*B_;           // 4,194,304 per dir
static constexpr size_t SXP  = 2*SXPC;
// whh packs: per layer: [2 dir][512 u][512 k][4 gate]
static constexpr size_t OWHH0 = OXP + SXP;
static constexpr size_t SWHH  = (size_t)2*512*512*4;          // 2,097,152
static constexpr size_t OWHH1 = OWHH0 + SWHH;
// wih packs: [2 dir][128 g][K][16 jj]
static constexpr size_t OWIH0 = OWHH1 + SWHH;
static constexpr size_t SWIH0 = (size_t)2*2048*256;
static constexpr size_t OWIH1 = OWIH0 + SWIH0;
static constexpr size_t SWIH1 = (size_t)2*2048*1024;
// wout pack: [1024 k][32]
static constexpr size_t OWOUT = OWIH1 + SWIH1;
static constexpr size_t SWOUT = (size_t)1024*32;
// h history: [2 layer][2 dir][HSLOT][128 k4][64 b][4]
static constexpr size_t OHH   = OWOUT + SWOUT;
static constexpr size_t SHHL  = (size_t)2*HSLOT*32768;        // per layer (2 dir)
static constexpr size_t SHH   = 2*SHHL;
// cbuf: [2 layer][2 dir][512 u][64 b]
static constexpr size_t OCB   = OHH + SHH;
static constexpr size_t SCB   = (size_t)2*2*512*64;
// barrier flags: [2 layer][2 dir][128 blocks x 16 ints]
static constexpr size_t OBAR  = OCB + SCB;
static constexpr size_t SBAR  = (size_t)2*2*128*16;           // 8192 ints
// feats: [T][B][32]
static constexpr size_t OFE   = OBAR + SBAR;
static constexpr size_t SFE   = (size_t)T_*B_*NTAG;
// backpointers (bytes): [255][B][32]
static constexpr size_t OBP   = OFE + SFE;
static constexpr size_t SBP   = (size_t)T_*B_*NTAG/4;
static constexpr size_t WS_FLOATS = OBP + SBP;                // ~226.1 MB

__device__ __forceinline__ float sigf(float x){ return 1.0f/(1.0f + expf(-x)); }

// ---------------- weight packing ----------------
// whh pack (per dir matrix): out[(u*512 + k)*4 + gate] = w[(gate*512 + u)*512 + k]
__global__ void pack_whh(const float* __restrict__ w, float* __restrict__ out){
  int id = blockIdx.x*256 + threadIdx.x;            // grid 4096
  int gate = id & 3, k = (id>>2) & 511, u = id >> 11;
  out[id] = w[((size_t)gate*512 + u)*512 + k];
}
// wih pack: out[g][k][jj] jj in [0,16), row = g*16+jj
__global__ void pack_wih(const float* __restrict__ w, float* __restrict__ out, int K, int kshift){
  int id = blockIdx.x*256 + threadIdx.x;            // 2048*K threads
  int k = id & (K-1); int jj = (id>>kshift)&15; int g = id>>(kshift+4);
  out[((size_t)g*K + k)*16 + jj] = w[(size_t)(g*16+jj)*K + k];
}
// wout pack: out[k][32]
__global__ void pack_wout(const float* __restrict__ w, float* __restrict__ out){
  int id = blockIdx.x*256 + threadIdx.x;            // 32*1024
  int k = id & 1023, jj = id>>10;
  out[k*32 + jj] = w[id];
}

// ---------------- embedding gather (to [t][e4][b][4]) ----------------
__global__ void gather_emb(const int* __restrict__ sent, const float* __restrict__ emb,
                           float* __restrict__ x0){
  int t = blockIdx.x; int lane = threadIdx.x & 63; int w = threadIdx.x >> 6;
  int s = sent[t*B_ + lane];
  const float4* er = (const float4*)emb + (size_t)s*(E_/4);
  float4* xo = (float4*)x0 + (size_t)t*64*64;
  #pragma unroll
  for (int q=0; q<16; ++q){
    int e4 = w*16 + q;
    xo[e4*64 + lane] = er[e4];
  }
}

// ---------------- input projection GEMM (per time-chunk) ----------------
// Grid (jg=64, i=CHK, dir=2): jg fastest-varying so each W-slice is pinned to one
// XCD (id%8 == jg%8) and stays L2-resident across t; 64 same-t blocks are adjacent
// so x[t] is fetched ~once per XCD instead of once per block.
// R7: weight reads as explicit float4 (jj is contiguous in the pack) -- the
// scalar form was VMEM-issue bound (64 dword loads per 128 FMA => measured
// ~455us/launch at K=1024, ~4x the FMA floor). Accumulation order unchanged.
__global__ __launch_bounds__(256) void proj_kernel(
    const float* __restrict__ xin, const float* __restrict__ wpack,
    const float* __restrict__ bihf, const float* __restrict__ bhhf,
    const float* __restrict__ bihr, const float* __restrict__ bhhr,
    float* __restrict__ xp, int K, int t0){
  int jg = blockIdx.x, i = blockIdx.y, dir = blockIdx.z;
  int t = dir ? (T_-1 - (t0 + i)) : (t0 + i);
  int lane = threadIdx.x & 63;
  int w = __builtin_amdgcn_readfirstlane((int)threadIdx.x) >> 6;
  int kq = K >> 2;                 // k per wave
  int n4 = kq >> 2;                // float4 iters
  int k40 = (w*kq) >> 2;
  const float4* xi = (const float4*)xin + (size_t)t*(K>>2)*64;
  size_t pstride = (size_t)K*16;
  const float* wp = wpack + (size_t)dir*2048*K + (size_t)(jg*2)*pstride + (size_t)w*kq*16;
  float acc[2][16];
  #pragma unroll
  for (int p=0;p<2;p++)
    #pragma unroll
    for (int jj=0;jj<16;jj++) acc[p][jj] = 0.f;
  for (int k4=0; k4<n4; ++k4){
    float4 h = xi[(k40+k4)*64 + lane];
    float hv[4] = {h.x, h.y, h.z, h.w};
    #pragma unroll
    for (int p=0;p<2;p++){
      const float4* wv4 = (const float4*)(wp + p*pstride + k4*64);
      #pragma unroll
      for (int ii=0;ii<4;ii++){
        float4 wa = wv4[ii*4+0];
        float4 wb = wv4[ii*4+1];
        float4 wc = wv4[ii*4+2];
        float4 wd = wv4[ii*4+3];
        acc[p][ 0] = fmaf(wa.x, hv[ii], acc[p][ 0]);
        acc[p][ 1] = fmaf(wa.y, hv[ii], acc[p][ 1]);
        acc[p][ 2] = fmaf(wa.z, hv[ii], acc[p][ 2]);
        acc[p][ 3] = fmaf(wa.w, hv[ii], acc[p][ 3]);
        acc[p][ 4] = fmaf(wb.x, hv[ii], acc[p][ 4]);
        acc[p][ 5] = fmaf(wb.y, hv[ii], acc[p][ 5]);
        acc[p][ 6] = fmaf(wb.z, hv[ii], acc[p][ 6]);
        acc[p][ 7] = fmaf(wb.w, hv[ii], acc[p][ 7]);
        acc[p][ 8] = fmaf(wc.x, hv[ii], acc[p][ 8]);
        acc[p][ 9] = fmaf(wc.y, hv[ii], acc[p][ 9]);
        acc[p][10] = fmaf(wc.z, hv[ii], acc[p][10]);
        acc[p][11] = fmaf(wc.w, hv[ii], acc[p][11]);
        acc[p][12] = fmaf(wd.x, hv[ii], acc[p][12]);
        acc[p][13] = fmaf(wd.y, hv[ii], acc[p][13]);
        acc[p][14] = fmaf(wd.z, hv[ii], acc[p][14]);
        acc[p][15] = fmaf(wd.w, hv[ii], acc[p][15]);
      }
    }
  }
  __shared__ float red[4][32][64];
  #pragma unroll
  for (int p=0;p<2;p++)
    #pragma unroll
    for (int jj=0;jj<16;jj++) red[w][p*16+jj][lane] = acc[p][jj];
  __syncthreads();
  const float* b1 = dir ? bihr : bihf;
  const float* b2 = dir ? bhhr : bhhf;
  float* xpd = xp + (size_t)dir*SXPC + (size_t)i*2048*64;
  #pragma unroll
  for (int q=0;q<8;q++){
    int rr = w*8 + q;
    float v = red[0][rr][lane] + red[1][rr][lane] + red[2][rr][lane] + red[3][rr][lane];
    int row = jg*32 + rr;
    v += b1[row] + b2[row];
    xpd[(size_t)row*64 + lane] = v;
  }
}

// ---------------- persistent bidirectional LSTM (one time-chunk) ----------------
// R0 kernel verbatim (the 386us/launch baseline): K-SPLIT layout, wave w loads
// its 128-k quarter of h, computes partials for 4 units x 4 gates, LDS-reduce,
// wave w finalizes unit uo = g*4+w (c in register). Fence-free flag protocol:
// relaxed agent atomics + vmcnt(0) drain, rolling 33-slot h history;
// kernel-boundary implicit acquire/release handles slot reuse across launches.
__global__ __launch_bounds__(256,1) void rec_kernel(
    const float* __restrict__ xp, const float* __restrict__ whh,
    float* __restrict__ xout, float* __restrict__ hh, float* __restrict__ cb0,
    int* __restrict__ flags, int step0, int nsteps){
  int bid = blockIdx.x;
  int dir = bid & 1, g = bid >> 1;
  int lane = threadIdx.x & 63;
  int w = __builtin_amdgcn_readfirstlane((int)threadIdx.x >> 6);
  const float* xpd = xp + (size_t)dir*SXPC;
  const float* wbase = whh + (size_t)dir*1048576 + (size_t)g*4*2048;  // [u][k][gate]
  float* hhd = hh + (size_t)dir*((size_t)HSLOT*32768);
  float* cb = cb0 + dir*32768;
  int* fl = flags + dir*(128*16);
  __shared__ float red[4][16][64];              // [wave][u*4+gate][lane]
  __shared__ float hlds[256];                   // [64 b][4 u]
  int uo = g*4 + w;                             // unit finalized by this wave
  float c = cb[uo*64 + lane];
  size_t xb = ((size_t)uo)*64 + lane;
  float x0v = xpd[xb], x1v = xpd[xb+32768], x2v = xpd[xb+65536], x3v = xpd[xb+98304];
  for (int s=0; s<nsteps; ++s){
    int gstep = step0 + s;
    int t = dir ? (T_-1-gstep) : gstep;
    const float4* hp = (const float4*)(hhd + (size_t)(gstep % HSLOT)*32768);
    // stage this wave's k-quarter into registers: 32 independent loads in flight
    float4 hreg[32];
    #pragma unroll
    for (int i=0;i<32;i++) hreg[i] = hp[(w*32+i)*64 + lane];
    float acc[4][4];
    #pragma unroll
    for (int cu=0;cu<4;cu++)
      #pragma unroll
      for (int gt=0;gt<4;gt++) acc[cu][gt]=0.f;
    #pragma unroll
    for (int i=0;i<32;i++){
      float hv[4] = {hreg[i].x, hreg[i].y, hreg[i].z, hreg[i].w};
      #pragma unroll
      for (int cu=0; cu<4; cu++){
        const float4* wr = (const float4*)(wbase + (size_t)cu*2048 + (size_t)(w*128 + i*4)*4);
        #pragma unroll
        for (int kk=0;kk<4;kk++){
          float4 w4 = wr[kk];
          acc[cu][0] = fmaf(w4.x, hv[kk], acc[cu][0]);
          acc[cu][1] = fmaf(w4.y, hv[kk], acc[cu][1]);
          acc[cu][2] = fmaf(w4.z, hv[kk], acc[cu][2]);
          acc[cu][3] = fmaf(w4.w, hv[kk], acc[cu][3]);
        }
      }
    }
    #pragma unroll
    for (int cu=0;cu<4;cu++)
      #pragma unroll
      for (int gt=0;gt<4;gt++) red[w][cu*4+gt][lane] = acc[cu][gt];
    __syncthreads();
    float gv[4];
    #pragma unroll
    for (int gt=0;gt<4;gt++)
      gv[gt] = red[0][w*4+gt][lane] + red[1][w*4+gt][lane]
             + red[2][w*4+gt][lane] + red[3][w*4+gt][lane];
    gv[0] += x0v; gv[1] += x1v; gv[2] += x2v; gv[3] += x3v;
    float iv = sigf(gv[0]), fv = sigf(gv[1]);
    float gg = tanhf(gv[2]), ov = sigf(gv[3]);
    c = fv*c + iv*gg;
    float h = ov*tanhf(c);
    hlds[lane*4 + w] = h;
    __syncthreads();
    if (w == 0){
      // publish h quad: write-through coherent stores (2x u64 per lane = 1 KB)
      float4 hv4 = ((const float4*)hlds)[lane];
      union { float4 f; unsigned long long q[2]; } uu; uu.f = hv4;
      unsigned long long* dst = (unsigned long long*)
          (hhd + (size_t)((gstep+1) % HSLOT)*32768 + (size_t)g*256 + (size_t)lane*4);
      __hip_atomic_store(dst+0, uu.q[0], __ATOMIC_RELAXED, __HIP_MEMORY_SCOPE_AGENT);
      __hip_atomic_store(dst+1, uu.q[1], __ATOMIC_RELAXED, __HIP_MEMORY_SCOPE_AGENT);
    } else if (w == 1){
      float4 hv4 = ((const float4*)hlds)[lane];
      float4* xo = (float4*)(xout + (size_t)t*65536 + (size_t)(dir*128 + g)*256);
      xo[lane] = hv4;
    }
    if (s < nsteps-1){
      if (w == 0){
        asm volatile("s_waitcnt vmcnt(0)" ::: "memory");   // h stores at coherence point
      }
      __syncthreads();
      if (threadIdx.x == 0)
        __hip_atomic_store(&fl[g*16], gstep+1, __ATOMIC_RELAXED, __HIP_MEMORY_SCOPE_AGENT);
      // prefetch next step's xp gates (overlaps poll latency)
      size_t xb2 = ((size_t)(s+1)*2048 + uo)*64 + lane;
      x0v = xpd[xb2]; x1v = xpd[xb2+32768]; x2v = xpd[xb2+65536]; x3v = xpd[xb2+98304];
      int tid = threadIdx.x;
      if (tid < 128){
        int target = gstep+1;
        int spins = 0;
        while (__hip_atomic_load(&fl[tid*16], __ATOMIC_RELAXED, __HIP_MEMORY_SCOPE_AGENT) < target){
          __builtin_amdgcn_s_sleep(1);
          if (++spins > (1<<22)) break;   // failsafe
        }
      }
      __syncthreads();
      asm volatile("" ::: "memory");      // keep h loads after the poll
    }
  }
  cb[uo*64 + lane] = c;   // persist cell state for the next chunk launch
}

// ---------------- output projection (feats) ----------------
// R7: same float4 weight-load fix as proj (j contiguous in wout pack).
__global__ __launch_bounds__(256) void feats_kernel(
    const float* __restrict__ x2, const float* __restrict__ wout,
    const float* __restrict__ bout, float* __restrict__ feats){
  int t = blockIdx.x; int lane = threadIdx.x & 63;
  int w = __builtin_amdgcn_readfirstlane((int)threadIdx.x) >> 6;
  const float4* xi = (const float4*)x2 + (size_t)t*16384;
  const float* wp = wout + (size_t)w*256*32;
  float acc[32];
  #pragma unroll
  for (int j=0;j<32;j++) acc[j] = 0.f;
  for (int k4=0;k4<64;k4++){
    float4 h = xi[(w*64 + k4)*64 + lane];
    float hv[4] = {h.x, h.y, h.z, h.w};
    const float4* wv4 = (const float4*)(wp + k4*128);
    #pragma unroll
    for (int ii=0;ii<4;ii++){
      #pragma unroll
      for (int q=0;q<8;q++){
        float4 w4 = wv4[ii*8 + q];
        acc[q*4+0] = fmaf(w4.x, hv[ii], acc[q*4+0]);
        acc[q*4+1] = fmaf(w4.y, hv[ii], acc[q*4+1]);
        acc[q*4+2] = fmaf(w4.z, hv[ii], acc[q*4+2]);
        acc[q*4+3] = fmaf(w4.w, hv[ii], acc[q*4+3]);
      }
    }
  }
  __shared__ float red[4][32][64];
  #pragma unroll
  for (int j=0;j<32;j++) red[w][j][lane] = acc[j];
  __syncthreads();
  __shared__ float tr[64*33];
  #pragma unroll
  for (int q=0;q<8;q++){
    int j = w*8 + q;
    float v = red[0][j][lane]+red[1][j][lane]+red[2][j][lane]+red[3][j][lane] + bout[j];
    tr[lane*33 + j] = v;
  }
  __syncthreads();
  float* fo = feats + (size_t)t*2048;
  int tid = threadIdx.x;
  #pragma unroll
  for (int q=0;q<8;q++){
    int idx = tid*8 + q;                 // = b*32 + j
    fo[idx] = tr[(idx>>5)*33 + (idx&31)];
  }
}

// ---------------- Viterbi decode ----------------
__global__ __launch_bounds__(64) void viterbi_kernel(
    const float* __restrict__ feats, const float* __restrict__ trans,
    const float* __restrict__ start, const float* __restrict__ stop,
    unsigned char* __restrict__ bp, float* __restrict__ out){
  int lane = threadIdx.x & 63;
  int b = blockIdx.x*2 + (lane>>5);
  int j = lane & 31;
  int base = lane & 32;
  float tr[32];
  #pragma unroll
  for (int k=0;k<32;k++) tr[k] = trans[j*32+k];
  float dp = start[j] + feats[b*32 + j];
  for (int t=1;t<T_;t++){
    float best = __shfl(dp, base, 64) + tr[0];
    int arg = 0;
    #pragma unroll
    for (int k=1;k<32;k++){
      float v = __shfl(dp, base + k, 64) + tr[k];
      if (v > best){ best = v; arg = k; }
    }
    dp = best + feats[((size_t)t*64 + b)*32 + j];
    bp[(size_t)(t-1)*2048 + b*32 + j] = (unsigned char)arg;
  }
  dp += stop[j];
  float bv = dp; int bi = j;
  #pragma unroll
  for (int off=1; off<32; off<<=1){
    float ov = __shfl_xor(bv, off, 64);
    int oi   = __shfl_xor(bi, off, 64);
    if (ov > bv || (ov == bv && oi < bi)){ bv = ov; bi = oi; }
  }
  if (j == 0){
    out[b] = bv;
    int cur = bi;
    out[64 + 255*64 + b] = (float)cur;
    for (int t=254;t>=0;t--){
      cur = bp[(size_t)t*2048 + b*32 + cur];
      out[64 + t*64 + b] = (float)cur;
    }
  }
}

// ---------------- launcher ----------------
extern "C" void kernel_launch(void* const* d_in, const int* in_sizes, int n_in,
                              void* d_out, int out_size, void* d_ws, size_t ws_size,
                              hipStream_t stream){
  const int*   sent      = (const int*)  d_in[0];
  const float* emb       = (const float*)d_in[1];
  const float* w_ih_l0f  = (const float*)d_in[2];
  const float* w_hh_l0f  = (const float*)d_in[3];
  const float* b_ih_l0f  = (const float*)d_in[4];
  const float* b_hh_l0f  = (const float*)d_in[5];
  const float* w_ih_l0r  = (const float*)d_in[6];
  const float* w_hh_l0r  = (const float*)d_in[7];
  const float* b_ih_l0r  = (const float*)d_in[8];
  const float* b_hh_l0r  = (const float*)d_in[9];
  const float* w_ih_l1f  = (const float*)d_in[10];
  const float* w_hh_l1f  = (const float*)d_in[11];
  const float* b_ih_l1f  = (const float*)d_in[12];
  const float* b_hh_l1f  = (const float*)d_in[13];
  const float* w_ih_l1r  = (const float*)d_in[14];
  const float* w_hh_l1r  = (const float*)d_in[15];
  const float* b_ih_l1r  = (const float*)d_in[16];
  const float* b_hh_l1r  = (const float*)d_in[17];
  const float* W_out     = (const float*)d_in[18];
  const float* b_out     = (const float*)d_in[19];
  const float* trans     = (const float*)d_in[20];
  const float* start_t   = (const float*)d_in[21];
  const float* stop_t    = (const float*)d_in[22];
  float* ws  = (float*)d_ws;
  float* out = (float*)d_out;

  // Guard: if scratch is too small, bail out cleanly (absmax fail, not a GPU fault).
  if (ws_size < WS_FLOATS * sizeof(float)) return;

  // zero h-history/c/flag state (ws is re-poisoned to 0xAA before every timed launch)
  hipMemsetAsync(ws + OHH, 0, (SHH + SCB + SBAR)*sizeof(float), stream);

  // weight packing (idempotent, runs every call)
  pack_whh<<<4096,256,0,stream>>>(w_hh_l0f, ws + OWHH0);
  pack_whh<<<4096,256,0,stream>>>(w_hh_l0r, ws + OWHH0 + 1048576);
  pack_whh<<<4096,256,0,stream>>>(w_hh_l1f, ws + OWHH1);
  pack_whh<<<4096,256,0,stream>>>(w_hh_l1r, ws + OWHH1 + 1048576);
  pack_wih<<<2048,256,0,stream>>>(w_ih_l0f, ws + OWIH0,           256, 8);
  pack_wih<<<2048,256,0,stream>>>(w_ih_l0r, ws + OWIH0 + 524288,  256, 8);
  pack_wih<<<8192,256,0,stream>>>(w_ih_l1f, ws + OWIH1,           1024, 10);
  pack_wih<<<8192,256,0,stream>>>(w_ih_l1r, ws + OWIH1 + 2097152, 1024, 10);
  pack_wout<<<128,256,0,stream>>>(W_out, ws + OWOUT);

  gather_emb<<<256,256,0,stream>>>(sent, emb, ws + OX0);

  const int NCH = T_ / CHK;   // 8 chunks per layer
  dim3 gp(64, CHK, 2);        // jg fastest: XCD-pinned W-slices, same-t adjacency
  int* bar = (int*)(ws + OBAR);

  // layer 0: proj chunk -> rec chunk  (x0 -> x1)
  for (int c = 0; c < NCH; ++c){
    proj_kernel<<<gp,256,0,stream>>>(ws+OX0, ws+OWIH0,
                                     b_ih_l0f,b_hh_l0f,b_ih_l0r,b_hh_l0r,
                                     ws+OXP, 256, c*CHK);
    rec_kernel<<<256,256,0,stream>>>(ws+OXP, ws+OWHH0, ws+OX1,
                                     ws+OHH, ws+OCB, bar, c*CHK, CHK);
  }
  // layer 1: x1 -> x2 (x0 alias is dead by now)
  for (int c = 0; c < NCH; ++c){
    proj_kernel<<<gp,256,0,stream>>>(ws+OX1, ws+OWIH1,
                                     b_ih_l1f,b_hh_l1f,b_ih_l1r,b_hh_l1r,
                                     ws+OXP, 1024, c*CHK);
    rec_kernel<<<256,256,0,stream>>>(ws+OXP, ws+OWHH1, ws+OX2,
                                     ws+OHH+SHHL, ws+OCB+65536,
                                     bar + 4096, c*CHK, CHK);
  }
  // emission scores + decode
  feats_kernel<<<256,256,0,stream>>>(ws+OX2, ws+OWOUT, b_out, ws+OFE);
  viterbi_kernel<<<32,64,0,stream>>>(ws+OFE, trans, start_t, stop_t,
                                     (unsigned char*)(ws+OBP), out);
}